// Round 1
// baseline (15.327 us; speedup 1.0000x reference)
//
#include <hip/hip_runtime.h>

// Reference collapses: softmax over a size-1 axis == 1.0, so m1 == m2 == ones.
//   mask1 = mask2 = C = 256.0   (shape N,H,W = 8,14,14 -> 1568 elems each)
//   v1[n,c] = mean_{h,w} l1_org[n,c,h,w]   (8,256 -> 2048 elems)
//   v2[n,c] = mean_{h,w} l2_org[n,c,h,w]
// Output flat layout: mask1 [0,1568) | v1 [1568,3616) | mask2 [3616,5184) | v2 [5184,7232)

#define HW   196    // 14*14
#define NC   2048   // N*C = 8*256
#define MASK_ELEMS 1568  // N*H*W

__global__ __launch_bounds__(64) void lra_kernel(const float* __restrict__ l1,
                                                 const float* __restrict__ l2,
                                                 float* __restrict__ out) {
    const int b    = blockIdx.x;
    const int lane = threadIdx.x;  // 0..63, one wave per block

    if (b < 2 * NC) {
        // spatial mean for one (tensor, n, c)
        const bool first = (b < NC);
        const int  nc    = first ? b : b - NC;
        const float* p   = (first ? l1 : l2) + (size_t)nc * HW;

        float s = 0.0f;
        #pragma unroll
        for (int i = lane; i < HW; i += 64) s += p[i];   // lanes 0..3 do 4 elems, rest 3

        // full-wave butterfly reduce (wave = 64 on CDNA)
        #pragma unroll
        for (int off = 32; off > 0; off >>= 1)
            s += __shfl_down(s, off, 64);

        if (lane == 0) {
            const int base = first ? MASK_ELEMS : (2 * MASK_ELEMS + NC);  // 1568 or 5184
            out[base + nc] = s * (1.0f / (float)HW);
        }
    } else {
        // constant mask fill: 2*1568 elements of 256.0
        const int i = (b - 2 * NC) * 64 + lane;
        if (i < 2 * MASK_ELEMS) {
            const int off = (i < MASK_ELEMS) ? i : (i - MASK_ELEMS) + (MASK_ELEMS + NC); // mask1 or mask2 region
            out[off] = 256.0f;
        }
    }
}

extern "C" void kernel_launch(void* const* d_in, const int* in_sizes, int n_in,
                              void* d_out, int out_size, void* d_ws, size_t ws_size,
                              hipStream_t stream) {
    const float* l1 = (const float*)d_in[0];
    const float* l2 = (const float*)d_in[1];
    // d_in[2] (w) is unused: the attention masks collapse to ones.
    float* out = (float*)d_out;

    const int mean_blocks = 2 * NC;                       // 4096
    const int mask_blocks = (2 * MASK_ELEMS + 63) / 64;   // 49
    lra_kernel<<<mean_blocks + mask_blocks, 64, 0, stream>>>(l1, l2, out);
}

// Round 2
// 11.165 us; speedup vs baseline: 1.3728x; 1.3728x over previous
//
#include <hip/hip_runtime.h>

// Reference collapses: softmax over a size-1 axis == 1.0, so m1 == m2 == ones.
//   mask1 = mask2 = 256.0 (N,H,W = 8,14,14 -> 1568 elems each)
//   v1[n,c] = mean_{h,w} l1_org[n,c,h,w]   (8,256 -> 2048 elems), v2 likewise
// Output flat: mask1 [0,1568) | v1 [1568,3616) | mask2 [3616,5184) | v2 [5184,7232)

#define HW        196    // 14*14  == 49 float4
#define NC        2048   // N*C
#define MASKELEMS 1568   // N*H*W

__global__ __launch_bounds__(256) void lra_kernel(const float* __restrict__ l1,
                                                  const float* __restrict__ l2,
                                                  float* __restrict__ out) {
    const int tid  = threadIdx.x;
    const int lane = tid & 63;
    const int wave = tid >> 6;                    // 0..3
    const int row  = blockIdx.x * 4 + wave;       // 0..4095 : [0,NC)=l1 rows, [NC,2*NC)=l2 rows

    // ---- spatial mean: one wave per (tensor, n, c) row ----
    const bool first = (row < NC);
    const int  nc    = first ? row : row - NC;
    const float* p   = (first ? l1 : l2) + (size_t)nc * HW;

    float s = 0.0f;
    if (lane < 49) {                              // 49 float4 = 196 floats, base 16B-aligned
        float4 v = reinterpret_cast<const float4*>(p)[lane];
        s = (v.x + v.y) + (v.z + v.w);
    }
    #pragma unroll
    for (int off = 32; off > 0; off >>= 1)
        s += __shfl_down(s, off, 64);

    if (lane == 0) {
        const int base = first ? MASKELEMS : (2 * MASKELEMS + NC);  // 1568 or 5184
        out[base + nc] = s * (1.0f / (float)HW);
    }

    // ---- constant mask fill folded in: first 3136 global threads ----
    const int t = blockIdx.x * 256 + tid;
    if (t < 2 * MASKELEMS) {
        const int off = (t < MASKELEMS) ? t : (t - MASKELEMS) + (MASKELEMS + NC);
        out[off] = 256.0f;
    }
}

extern "C" void kernel_launch(void* const* d_in, const int* in_sizes, int n_in,
                              void* d_out, int out_size, void* d_ws, size_t ws_size,
                              hipStream_t stream) {
    const float* l1 = (const float*)d_in[0];
    const float* l2 = (const float*)d_in[1];
    // d_in[2] (w) unused: attention masks collapse to ones.
    float* out = (float*)d_out;

    lra_kernel<<<1024, 256, 0, stream>>>(l1, l2, out);  // 1024 blocks x 4 waves = 4096 rows
}